// Round 3
// baseline (1637.461 us; speedup 1.0000x reference)
//
#include <hip/hip_runtime.h>

typedef unsigned short u16;
typedef __attribute__((ext_vector_type(8))) __bf16 bf16x8;
typedef __attribute__((ext_vector_type(4))) float floatx4;

__device__ inline float bf2f(u16 u) {
  union { unsigned u; float f; } v; v.u = ((unsigned)u) << 16; return v.f;
}
__device__ inline u16 f2bf(float f) {
  union { float f; unsigned u; } v; v.f = f;
  unsigned r = v.u + 0x7fffu + ((v.u >> 16) & 1u);
  return (u16)(r >> 16);
}

__device__ inline void glds16(const u16* g, u16* l) {
  __builtin_amdgcn_global_load_lds((const __attribute__((address_space(1))) void*)g,
                                   (__attribute__((address_space(3))) void*)l, 16, 0, 0);
}

// ---------------- dtype probe: fp32-as-u16 halves have wild exponents ----------------
__global__ __launch_bounds__(256) void detect_k(const u16* __restrict__ w, int* flag)
{
  __shared__ int cnt;
  if (threadIdx.x == 0) cnt = 0;
  __syncthreads();
  int c = 0;
  for (int i = threadIdx.x; i < 16384; i += 256) {
    const int e = (w[i] >> 7) & 0xFF;
    if (e < 64 || e > 191) ++c;
  }
  atomicAdd(&cnt, c);
  __syncthreads();
  if (threadIdx.x == 0) *flag = (cnt > 256) ? 1 : 0;   // 1 => inputs are fp32
}

// ---------------- x -> bf16 (copy or downcast), 4 elems/thread ----------------
__global__ __launch_bounds__(256) void cast_x_k(const void* __restrict__ in,
                                                u16* __restrict__ out,
                                                int n4, const int* __restrict__ flag)
{
  const int i = blockIdx.x * 256 + threadIdx.x;
  if (i >= n4) return;
  if (*flag) {
    const float4 v = ((const float4*)in)[i];
    u16 o0 = f2bf(v.x), o1 = f2bf(v.y), o2 = f2bf(v.z), o3 = f2bf(v.w);
    uint2 p; p.x = (unsigned)o0 | ((unsigned)o1 << 16); p.y = (unsigned)o2 | ((unsigned)o3 << 16);
    ((uint2*)out)[i] = p;
  } else {
    ((uint2*)out)[i] = ((const uint2*)in)[i];
  }
}

// ---------------- cast+transpose: in [R,C] (flag? f32 : bf16) -> bf16 [C,R] ----------------
__global__ __launch_bounds__(256) void ct_transpose_k(const void* __restrict__ in,
                                                      u16* __restrict__ out,
                                                      int R, int C, const int* __restrict__ flag)
{
  __shared__ u16 tile[32][33];
  const int f = *flag;
  const int c0 = blockIdx.x * 32, r0 = blockIdx.y * 32;
  const int tx = threadIdx.x & 31, ty = threadIdx.x >> 5;
#pragma unroll
  for (int i = ty; i < 32; i += 8) {
    const size_t idx = (size_t)(r0 + i) * C + (c0 + tx);
    tile[i][tx] = f ? f2bf(((const float*)in)[idx]) : ((const u16*)in)[idx];
  }
  __syncthreads();
#pragma unroll
  for (int i = ty; i < 32; i += 8)
    out[(size_t)(c0 + i) * R + (r0 + tx)] = tile[tx][i];
}

// ---------------- bias -> fp32 ----------------
__global__ __launch_bounds__(256) void bias_cast_k(const void* __restrict__ in,
                                                   float* __restrict__ out,
                                                   int n, const int* __restrict__ flag)
{
  const int i = blockIdx.x * 256 + threadIdx.x;
  if (i >= n) return;
  out[i] = *flag ? ((const float*)in)[i] : bf2f(((const u16*)in)[i]);
}

// ---------------- GEMM C[M,N] = A[M,K] @ Bt[N,K]^T (+bias), bf16 MFMA ----------------
// 256x256 tile, 8 waves (2M x 4N), BK=32, 2-slot LDS ring (64 KiB) -> 2 blocks/CU
// (4 waves/SIMD). With two INDEPENDENT blocks co-resident, one block's MFMA burst
// overlaps the other block's LDS-read drain (m114 implicit wave-level overlap) --
// the 128 KiB 4-ring forced 1 block/CU and fully serialized the LDS and MFMA pipes
// (measured ~3500 cyc/K-tile vs max-pipe floor ~1535). Prefetch depth 1: issue
// kt+1's DMA at top of kt, fused vmcnt(0)+barrier at tile end (issue-to-wait
// distance ~ one tile of compute). XOR-swizzled LDS (16B slot h ^= line&7 within
// 128B lines of 2 rows), inverse-swizzled per-lane global source + linear
// global_load_lds dest, bijective XCD swizzle + M-major order, setprio on MFMA.
// Requires M%256==0, N%256==0, K%32==0, K>=64.
__global__ __launch_bounds__(512, 4) void gemm256(
    const u16* __restrict__ A, const u16* __restrict__ Bt,
    const float* __restrict__ bias, void* __restrict__ C,
    int M, int N, int K, const int* __restrict__ flag, int flagOut)
{
  __shared__ u16 smem[32768];   // A ring: [0..16383] (2x8192), B ring: [16384..32767]
  const int t = threadIdx.x;
  const int wave = t >> 6, lane = t & 63;
  const int quad = lane >> 4, l15 = lane & 15;
  const int wm = wave >> 2, wn = wave & 3;

  // bijective XCD swizzle (nwg%8 != 0 safe), then M-major so consecutive blocks
  // in an XCD chunk share the B-panel (384 KB, L2-resident)
  const int nwg = gridDim.x;
  const int q = nwg >> 3, r8 = nwg & 7;
  const int xcd = blockIdx.x & 7, loc = blockIdx.x >> 3;
  const int wg = (xcd < r8 ? xcd * (q + 1) : r8 * (q + 1) + (xcd - r8) * q) + loc;
  const int MT = M >> 8;
  const int mt = wg % MT, ntile = wg / MT;
  const size_t m0 = (size_t)mt << 8;
  const size_t n0 = (size_t)ntile << 8;

  // LDS read offsets (u16 units within one 8192-u16 slot).
  // Layout: line = row>>1 (128 B), slot h = (row&1)*4 + kgroup, stored h^(line&7).
  int addrA[8], addrB[4];
#pragma unroll
  for (int i = 0; i < 8; ++i) {
    const int row = wm * 128 + i * 16 + l15;
    const int hs = (((row & 1) << 2) | quad) ^ ((row >> 1) & 7);
    addrA[i] = (row >> 1) * 64 + hs * 8;
  }
#pragma unroll
  for (int j = 0; j < 4; ++j) {
    const int row = wn * 64 + j * 16 + l15;
    const int hs = (((row & 1) << 2) | quad) ^ ((row >> 1) & 7);
    addrB[j] = (row >> 1) * 64 + hs * 8;
  }

  // staging: issue p covers stored slots S = p*512 + wave*64 + lane; invert swizzle
  // to find the (row, kgroup) that must be fetched into slot S.
  const u16* aSrc[2]; const u16* bSrc[2]; int dstOff[2];
#pragma unroll
  for (int p = 0; p < 2; ++p) {
    const int S = p * 512 + wave * 64 + lane;
    const int line = S >> 3;
    const int h = (S & 7) ^ (line & 7);
    const int row = line * 2 + (h >> 2);
    const int g = (h & 3) * 8;
    aSrc[p] = A + (m0 + row) * (size_t)K + g;
    bSrc[p] = Bt + (n0 + row) * (size_t)K + g;
    dstOff[p] = p * 4096 + wave * 512;   // u16 units; HW adds lane*16 B
  }

  const int NTk = K >> 5;
  floatx4 acc[8][4] = {};

  // prologue: stage K-tile 0 into slot 0
#pragma unroll
  for (int p = 0; p < 2; ++p) glds16(aSrc[p], smem + dstOff[p]);
#pragma unroll
  for (int p = 0; p < 2; ++p) glds16(bSrc[p], smem + 16384 + dstOff[p]);
  asm volatile("s_waitcnt vmcnt(0)\n\ts_barrier" ::: "memory");

  for (int kt = 0; kt < NTk; ++kt) {
    const int rb = kt & 1;
    const u16* sA = smem + rb * 8192;
    const u16* sB = smem + 16384 + rb * 8192;

    // issue next tile's DMA first (slot (kt+1)&1, whose tile-(kt-1) readers all
    // consumed their data before the end-of-(kt-1) barrier)
    if (kt + 1 < NTk) {
      const int pre = (kt + 1) * 32;
      const int pr = (kt + 1) & 1;
      glds16(aSrc[0] + pre, smem + pr * 8192 + dstOff[0]);
      glds16(aSrc[1] + pre, smem + pr * 8192 + dstOff[1]);
      glds16(bSrc[0] + pre, smem + 16384 + pr * 8192 + dstOff[0]);
      glds16(bSrc[1] + pre, smem + 16384 + pr * 8192 + dstOff[1]);
    }

    // B first so the first MFMA's lgkm wait covers only 5 loads, not 12;
    // compiler inserts fine-grained lgkmcnt between reads and consuming MFMAs.
    bf16x8 b[4], a[8];
#pragma unroll
    for (int j = 0; j < 4; ++j) b[j] = *(const bf16x8*)(sB + addrB[j]);
#pragma unroll
    for (int i = 0; i < 8; ++i) a[i] = *(const bf16x8*)(sA + addrA[i]);

    __builtin_amdgcn_s_setprio(1);
#pragma unroll
    for (int i = 0; i < 8; ++i)
#pragma unroll
      for (int j = 0; j < 4; ++j)
        acc[i][j] = __builtin_amdgcn_mfma_f32_16x16x32_bf16(a[i], b[j], acc[i][j], 0, 0, 0);
    __builtin_amdgcn_s_setprio(0);

    // fused counted-wait + barrier: next tile's DMA (from ALL waves) has landed.
    if (kt + 1 < NTk) asm volatile("s_waitcnt vmcnt(0)\n\ts_barrier" ::: "memory");
  }

  // epilogue scratch overlaps live ring slots at 64 KiB -> sync first
  __syncthreads();

  // -------- epilogue: per-wave LDS repack -> coalesced 16B stores --------
  float bvj[4];
#pragma unroll
  for (int j = 0; j < 4; ++j)
    bvj[j] = bias ? bias[n0 + wn * 64 + j * 16 + l15] : 0.0f;

  if (flagOut && (*flag)) {
    // fp32 output: per m-frag 16 rows x 64 cols (stride 68 f32)
    float* scrf = (float*)smem + wave * 1088;
    float* Cf = (float*)C;
#pragma unroll
    for (int i = 0; i < 8; ++i) {
#pragma unroll
      for (int j = 0; j < 4; ++j)
#pragma unroll
        for (int rr = 0; rr < 4; ++rr)
          scrf[(quad * 4 + rr) * 68 + j * 16 + l15] = acc[i][j][rr] + bvj[j];
#pragma unroll
      for (int u = lane; u < 256; u += 64) {
        const int row = u >> 4, gr = u & 15;
        float4 vv = *(const float4*)(scrf + row * 68 + gr * 4);
        *(float4*)(Cf + (m0 + wm * 128 + i * 16 + row) * (size_t)N + n0 + wn * 64 + gr * 4) = vv;
      }
    }
  } else {
    // bf16 output: per m-frag 16 rows x 64 cols (stride 72 u16)
    u16* scr = smem + wave * 1152;
    u16* Cb = (u16*)C;
#pragma unroll
    for (int i = 0; i < 8; ++i) {
#pragma unroll
      for (int j = 0; j < 4; ++j)
#pragma unroll
        for (int rr = 0; rr < 4; ++rr)
          scr[(quad * 4 + rr) * 72 + j * 16 + l15] = f2bf(acc[i][j][rr] + bvj[j]);
#pragma unroll
      for (int u = lane; u < 128; u += 64) {
        const int row = u >> 3, gr = u & 7;
        int4 vv = *(const int4*)(scr + row * 72 + gr * 8);
        *(int4*)(Cb + (m0 + wm * 128 + i * 16 + row) * (size_t)N + n0 + wn * 64 + gr * 8) = vv;
      }
    }
  }
}

// ---------------- windowed attention ----------------
// one block (4 waves) per (b, l, head). K staged in LDS (XOR-64), V^T and P at
// stride 208 (2-way banks = free). LDS total 79.2 KB -> 2 blocks/CU.
__global__ __launch_bounds__(256, 2) void attn_win(
    const u16* __restrict__ qkv, u16* __restrict__ o)
{
  __shared__ u16 Ks[196 * 64];      // slot16B = row*8 + (g ^ (row&7))
  __shared__ u16 Vt[64 * 208];      // Vt[d][n], cols >=196 zero
  __shared__ u16 Pb[4][16 * 208];   // per-wave strip
  __shared__ int gtok[208];

  const int bid = blockIdx.x;
  const int h = bid % 12;
  const int l = (bid / 12) % 16;
  const int b = bid / 192;
  const int wr0 = (l >> 2) * 14, wc0 = (l & 3) * 14;
  const int baseTok = b * 3136;

  const int t = threadIdx.x, wave = t >> 6, lane = t & 63;
  const int quad = lane >> 4, l15 = lane & 15;

  if (t < 208) {
    const int nn = t < 196 ? t : 195;
    gtok[t] = baseTok + (wr0 + nn / 14) * 56 + wc0 + nn % 14;
  }
  __syncthreads();

  // stage K (rows 0..195, 8 d-groups, XOR layout)
  for (int u = t; u < 196 * 8; u += 256) {
    const int row = u >> 3, gg = u & 7;
    int4 kv = *(const int4*)(qkv + (size_t)gtok[row] * 2304 + 768 + h * 64 + gg * 8);
    *(int4*)(Ks + (row * 8 + (gg ^ (row & 7))) * 8) = kv;
  }
  // stage V transposed: Vt[d][n]
  for (int u = t; u < 208 * 8; u += 256) {
    const int n = u >> 3, dg = u & 7;
    int4 vv = {0, 0, 0, 0};
    if (n < 196)
      vv = *(const int4*)(qkv + (size_t)gtok[n] * 2304 + 1536 + h * 64 + dg * 8);
    const u16* pv = (const u16*)&vv;
#pragma unroll
    for (int j = 0; j < 8; ++j) Vt[(dg * 8 + j) * 208 + n] = pv[j];
  }
  __syncthreads();

  u16* Pw = &Pb[wave][0];
  const bf16x8 zerov = {};

  for (int rt = wave; rt < 13; rt += 4) {
    const int n0r = rt * 16;
    int qn = n0r + l15; if (qn > 195) qn = 195;
    const u16* qrow = qkv + (size_t)gtok[qn] * 2304 + h * 64;
    const bf16x8 aq0 = *(const bf16x8*)(qrow + quad * 8);
    const bf16x8 aq1 = *(const bf16x8*)(qrow + 32 + quad * 8);

    floatx4 s[13];
#pragma unroll
    for (int ct = 0; ct < 13; ++ct) {
      int kr = ct * 16 + l15; if (kr > 195) kr = 195;
      const bf16x8 bk0 = *(const bf16x8*)(Ks + (kr * 8 + (quad ^ (kr & 7))) * 8);
      const bf16x8 bk1 = *(const bf16x8*)(Ks + (kr * 8 + ((quad + 4) ^ (kr & 7))) * 8);
      floatx4 z = {};
      z = __builtin_amdgcn_mfma_f32_16x16x32_bf16(aq0, bk0, z, 0, 0, 0);
      z = __builtin_amdgcn_mfma_f32_16x16x32_bf16(aq1, bk1, z, 0, 0, 0);
      s[ct] = z;
    }

    // softmax: col = ct*16+l15, rows = n0r + quad*4 + r
    float mx[4], sm[4];
#pragma unroll
    for (int r = 0; r < 4; ++r) mx[r] = -3e38f;
#pragma unroll
    for (int ct = 0; ct < 13; ++ct) {
      const bool maskct = (ct == 12) && (l15 >= 4);
#pragma unroll
      for (int r = 0; r < 4; ++r) {
        float v = s[ct][r] * 0.125f;
        if (maskct) v = -3e38f;
        s[ct][r] = v;
        mx[r] = fmaxf(mx[r], v);
      }
    }
#pragma unroll
    for (int r = 0; r < 4; ++r)
      for (int off = 1; off < 16; off <<= 1)
        mx[r] = fmaxf(mx[r], __shfl_xor(mx[r], off, 64));
#pragma unroll
    for (int r = 0; r < 4; ++r) sm[r] = 0.0f;
#pragma unroll
    for (int ct = 0; ct < 13; ++ct)
#pragma unroll
      for (int r = 0; r < 4; ++r) {
        const float p = __expf(s[ct][r] - mx[r]);
        s[ct][r] = p;
        sm[r] += p;
      }
#pragma unroll
    for (int r = 0; r < 4; ++r)
      for (int off = 1; off < 16; off <<= 1)
        sm[r] += __shfl_xor(sm[r], off, 64);

    // P -> LDS (A-layout round trip); cols 0..207 fully covered
#pragma unroll
    for (int ct = 0; ct < 13; ++ct)
#pragma unroll
      for (int r = 0; r < 4; ++r)
        Pw[(quad * 4 + r) * 208 + ct * 16 + l15] = f2bf(s[ct][r]);

    // O = P @ V: 6 full K=32 steps + masked tail (k 192..207 real)
    floatx4 oacc[4] = {};
#pragma unroll
    for (int ks = 0; ks < 6; ++ks) {
      const bf16x8 ap = *(const bf16x8*)(Pw + l15 * 208 + ks * 32 + quad * 8);
#pragma unroll
      for (int nt = 0; nt < 4; ++nt) {
        const bf16x8 bv = *(const bf16x8*)(Vt + (nt * 16 + l15) * 208 + ks * 32 + quad * 8);
        oacc[nt] = __builtin_amdgcn_mfma_f32_16x16x32_bf16(ap, bv, oacc[nt], 0, 0, 0);
      }
    }
    {
      const int off = 192 + (quad & 1) * 8;
      bf16x8 ap = *(const bf16x8*)(Pw + l15 * 208 + off);
      if (quad >= 2) ap = zerov;
#pragma unroll
      for (int nt = 0; nt < 4; ++nt) {
        const bf16x8 bv = *(const bf16x8*)(Vt + (nt * 16 + l15) * 208 + off);
        oacc[nt] = __builtin_amdgcn_mfma_f32_16x16x32_bf16(ap, bv, oacc[nt], 0, 0, 0);
      }
    }

    float rs[4];
#pragma unroll
    for (int r = 0; r < 4; ++r) rs[r] = 1.0f / sm[r];

    // O -> Pw repack -> coalesced 16B stores
#pragma unroll
    for (int nt = 0; nt < 4; ++nt)
#pragma unroll
      for (int r = 0; r < 4; ++r)
        Pw[(quad * 4 + r) * 208 + nt * 16 + l15] = f2bf(oacc[nt][r] * rs[r]);
#pragma unroll
    for (int u = lane; u < 128; u += 64) {
      const int row = u >> 3, gr = u & 7;
      const int n = n0r + row;
      if (n < 196) {
        int4 vv = *(const int4*)(Pw + row * 208 + gr * 8);
        *(int4*)(o + (size_t)gtok[n] * 768 + h * 64 + gr * 8) = vv;
      }
    }
  }
}

extern "C" void kernel_launch(void* const* d_in, const int* in_sizes, int n_in,
                              void* d_out, int out_size, void* d_ws, size_t ws_size,
                              hipStream_t stream)
{
  const void* x     = d_in[0];  // [8,3136,768]   fp32 or bf16
  const void* wqkv  = d_in[1];  // [768,2304]
  const void* wproj = d_in[2];  // [768,768]
  const void* bproj = d_in[3];  // [768]

  char* ws = (char*)d_ws;
  int*   flag   = (int*)ws;                         // 16 B
  float* bprojF = (float*)(ws + 16);                // 768 f32
  u16*   wqkvT  = (u16*)(ws + 4096);                // 2304*768 bf16
  u16*   wprojT = (u16*)(ws + 3543040);             // 768*768  bf16
  u16*   qkvbuf = (u16*)(ws + 4722688);             // 25088*2304 bf16
  u16*   xb     = (u16*)(ws + 120328192);           // 25088*768 bf16 (reused as attn out)
  u16*   attno  = xb;

  detect_k<<<1, 256, 0, stream>>>((const u16*)wqkv, flag);
  cast_x_k<<<dim3(18816), 256, 0, stream>>>(x, xb, 4816896, flag);
  ct_transpose_k<<<dim3(72, 24), 256, 0, stream>>>(wqkv, wqkvT, 768, 2304, flag);
  ct_transpose_k<<<dim3(24, 24), 256, 0, stream>>>(wproj, wprojT, 768, 768, flag);
  bias_cast_k<<<dim3(3), 256, 0, stream>>>(bproj, bprojF, 768, flag);

  // QKV: M=25088 (98 tiles), N=2304 (9 tiles), K=768 -> 882 blocks
  gemm256<<<dim3(882), 512, 0, stream>>>(xb, wqkvT, (const float*)nullptr, qkvbuf,
                                         25088, 2304, 768, flag, 0);
  attn_win<<<dim3(1536), 256, 0, stream>>>(qkvbuf, attno);
  // proj: M=25088 (98 tiles), N=768 (3 tiles), K=768 -> 294 blocks
  gemm256<<<dim3(294), 512, 0, stream>>>(attno, wprojT, bprojF, d_out,
                                         25088, 768, 768, flag, 1);
}

// Round 4
// 390.751 us; speedup vs baseline: 4.1906x; 4.1906x over previous
//
#include <hip/hip_runtime.h>

typedef unsigned short u16;
typedef __attribute__((ext_vector_type(8))) __bf16 bf16x8;
typedef __attribute__((ext_vector_type(4))) float floatx4;

__device__ inline float bf2f(u16 u) {
  union { unsigned u; float f; } v; v.u = ((unsigned)u) << 16; return v.f;
}
__device__ inline u16 f2bf(float f) {
  union { float f; unsigned u; } v; v.f = f;
  unsigned r = v.u + 0x7fffu + ((v.u >> 16) & 1u);
  return (u16)(r >> 16);
}

__device__ inline void glds16(const u16* g, u16* l) {
  __builtin_amdgcn_global_load_lds((const __attribute__((address_space(1))) void*)g,
                                   (__attribute__((address_space(3))) void*)l, 16, 0, 0);
}

// ---------------- dtype probe: fp32-as-u16 halves have wild exponents ----------------
__global__ __launch_bounds__(256) void detect_k(const u16* __restrict__ w, int* flag)
{
  __shared__ int cnt;
  if (threadIdx.x == 0) cnt = 0;
  __syncthreads();
  int c = 0;
  for (int i = threadIdx.x; i < 16384; i += 256) {
    const int e = (w[i] >> 7) & 0xFF;
    if (e < 64 || e > 191) ++c;
  }
  atomicAdd(&cnt, c);
  __syncthreads();
  if (threadIdx.x == 0) *flag = (cnt > 256) ? 1 : 0;   // 1 => inputs are fp32
}

// ---------------- x -> bf16 (copy or downcast), 4 elems/thread ----------------
__global__ __launch_bounds__(256) void cast_x_k(const void* __restrict__ in,
                                                u16* __restrict__ out,
                                                int n4, const int* __restrict__ flag)
{
  const int i = blockIdx.x * 256 + threadIdx.x;
  if (i >= n4) return;
  if (*flag) {
    const float4 v = ((const float4*)in)[i];
    u16 o0 = f2bf(v.x), o1 = f2bf(v.y), o2 = f2bf(v.z), o3 = f2bf(v.w);
    uint2 p; p.x = (unsigned)o0 | ((unsigned)o1 << 16); p.y = (unsigned)o2 | ((unsigned)o3 << 16);
    ((uint2*)out)[i] = p;
  } else {
    ((uint2*)out)[i] = ((const uint2*)in)[i];
  }
}

// ---------------- cast+transpose: in [R,C] (flag? f32 : bf16) -> bf16 [C,R] ----------------
__global__ __launch_bounds__(256) void ct_transpose_k(const void* __restrict__ in,
                                                      u16* __restrict__ out,
                                                      int R, int C, const int* __restrict__ flag)
{
  __shared__ u16 tile[32][33];
  const int f = *flag;
  const int c0 = blockIdx.x * 32, r0 = blockIdx.y * 32;
  const int tx = threadIdx.x & 31, ty = threadIdx.x >> 5;
#pragma unroll
  for (int i = ty; i < 32; i += 8) {
    const size_t idx = (size_t)(r0 + i) * C + (c0 + tx);
    tile[i][tx] = f ? f2bf(((const float*)in)[idx]) : ((const u16*)in)[idx];
  }
  __syncthreads();
#pragma unroll
  for (int i = ty; i < 32; i += 8)
    out[(size_t)(c0 + i) * R + (r0 + tx)] = tile[tx][i];
}

// ---------------- bias -> fp32 ----------------
__global__ __launch_bounds__(256) void bias_cast_k(const void* __restrict__ in,
                                                   float* __restrict__ out,
                                                   int n, const int* __restrict__ flag)
{
  const int i = blockIdx.x * 256 + threadIdx.x;
  if (i >= n) return;
  out[i] = *flag ? ((const float*)in)[i] : bf2f(((const u16*)in)[i]);
}

// ---------------- GEMM C[M,N] = A[M,K] @ Bt[N,K]^T (+bias), bf16 MFMA ----------------
// 256x256 tile, 8 waves (2M x 4N), BK=32, 4-slot LDS ring (128 KiB), 1 block/CU
// (structural: acc[8][4] = 128 AGPR/thread forbids 2 blocks -- round-3 lesson).
// Key change: WITHIN-WAVE overlap of LDS reads and MFMA via partial register
// double-buffering. B frags are double-buffered (+16 VGPR, total ~116 <= 128 cap);
// the 32-MFMA tile splits into c1 = a03 x b_cur (overlaps the a47 ds_reads) and
// c2 = a47 x b_cur (overlaps NEXT tile's B ds_reads, issued after a mid-tile
// fused vmcnt(4)+barrier that publishes tile kt+1's DMA). DMA issued 2 tiles
// ahead at iter top; overwrite target = tile kt-2 whose reads were lgkm-drained
// before the previous barrier (race-free). Prior rounds measured ~3040 cyc/tile
// = LDS-drain + MFMA serialized; this targets ~1700 = max-pipe + small bubble.
// Requires M%256==0, N%256==0, K%32==0, K>=96.
__global__ __launch_bounds__(512, 2) void gemm256(
    const u16* __restrict__ A, const u16* __restrict__ Bt,
    const float* __restrict__ bias, void* __restrict__ C,
    int M, int N, int K, const int* __restrict__ flag, int flagOut)
{
  __shared__ u16 smem[65536];   // A ring: [0..32767] (4x8192), B ring: [32768..65535]
  const int t = threadIdx.x;
  const int wave = t >> 6, lane = t & 63;
  const int quad = lane >> 4, l15 = lane & 15;
  const int wm = wave >> 2, wn = wave & 3;

  // bijective XCD swizzle (nwg%8 != 0 safe), then M-major so consecutive blocks
  // in an XCD chunk share the B-panel (384 KB, L2-resident)
  const int nwg = gridDim.x;
  const int q = nwg >> 3, r8 = nwg & 7;
  const int xcd = blockIdx.x & 7, loc = blockIdx.x >> 3;
  const int wg = (xcd < r8 ? xcd * (q + 1) : r8 * (q + 1) + (xcd - r8) * q) + loc;
  const int MT = M >> 8;
  const int mt = wg % MT, ntile = wg / MT;
  const size_t m0 = (size_t)mt << 8;
  const size_t n0 = (size_t)ntile << 8;

  // LDS read offsets (u16 units within one 8192-u16 slot).
  // Layout: line = row>>1 (128 B), slot h = (row&1)*4 + kgroup, stored h^(line&7).
  int addrA[8], addrB[4];
#pragma unroll
  for (int i = 0; i < 8; ++i) {
    const int row = wm * 128 + i * 16 + l15;
    const int hs = (((row & 1) << 2) | quad) ^ ((row >> 1) & 7);
    addrA[i] = (row >> 1) * 64 + hs * 8;
  }
#pragma unroll
  for (int j = 0; j < 4; ++j) {
    const int row = wn * 64 + j * 16 + l15;
    const int hs = (((row & 1) << 2) | quad) ^ ((row >> 1) & 7);
    addrB[j] = (row >> 1) * 64 + hs * 8;
  }

  // staging: issue p covers stored slots S = p*512 + wave*64 + lane; invert swizzle
  // to find the (row, kgroup) that must be fetched into slot S.
  const u16* aSrc[2]; const u16* bSrc[2]; int dstOff[2];
#pragma unroll
  for (int p = 0; p < 2; ++p) {
    const int S = p * 512 + wave * 64 + lane;
    const int line = S >> 3;
    const int h = (S & 7) ^ (line & 7);
    const int row = line * 2 + (h >> 2);
    const int g = (h & 3) * 8;
    aSrc[p] = A + (m0 + row) * (size_t)K + g;
    bSrc[p] = Bt + (n0 + row) * (size_t)K + g;
    dstOff[p] = p * 4096 + wave * 512;   // u16 units; HW adds lane*16 B
  }

  const int NTk = K >> 5;
  floatx4 acc[8][4] = {};

  // prologue: stage K-tiles 0,1 into ring slots 0,1
#pragma unroll
  for (int pt = 0; pt < 2; ++pt) {
#pragma unroll
    for (int p = 0; p < 2; ++p) glds16(aSrc[p] + pt * 32, smem + pt * 8192 + dstOff[p]);
#pragma unroll
    for (int p = 0; p < 2; ++p) glds16(bSrc[p] + pt * 32, smem + 32768 + pt * 8192 + dstOff[p]);
  }
  // tile 0 landed (tile 1 in flight); fused so nothing slips between wait and sync
  asm volatile("s_waitcnt vmcnt(4)\n\ts_barrier" ::: "memory");

  bf16x8 bcur[4];
#pragma unroll
  for (int j = 0; j < 4; ++j) bcur[j] = *(const bf16x8*)(smem + 32768 + addrB[j]);

  for (int kt = 0; kt < NTk; ++kt) {
    const u16* sA = smem + (kt & 3) * 8192;

    // DMA(kt+2): earliest HBM issue. Overwrites slot (kt+2)&3 = tile kt-2, whose
    // reads (all waves) were lgkm-drained before the previous barrier.
    if (kt + 2 < NTk) {
      const int pre = (kt + 2) * 32;
      const int pr = (kt + 2) & 3;
      glds16(aSrc[0] + pre, smem + pr * 8192 + dstOff[0]);
      glds16(aSrc[1] + pre, smem + pr * 8192 + dstOff[1]);
      glds16(bSrc[0] + pre, smem + 32768 + pr * 8192 + dstOff[0]);
      glds16(bSrc[1] + pre, smem + 32768 + pr * 8192 + dstOff[1]);
    }

    // A reads for this tile; c1 only lgkm-waits the first 4 (a03), so the a47
    // drain overlaps the c1 MFMA cluster.
    bf16x8 a03[4], a47[4];
#pragma unroll
    for (int i = 0; i < 4; ++i) a03[i] = *(const bf16x8*)(sA + addrA[i]);
#pragma unroll
    for (int i = 0; i < 4; ++i) a47[i] = *(const bf16x8*)(sA + addrA[4 + i]);

    __builtin_amdgcn_s_setprio(1);
#pragma unroll
    for (int i = 0; i < 4; ++i)
#pragma unroll
      for (int j = 0; j < 4; ++j)
        acc[i][j] = __builtin_amdgcn_mfma_f32_16x16x32_bf16(a03[i], bcur[j], acc[i][j], 0, 0, 0);
    __builtin_amdgcn_s_setprio(0);

    if (kt + 1 < NTk) {
      // mid-tile fused counted-wait + barrier: publishes tile kt+1's DMA (all
      // waves). vmcnt(4) keeps DMA(kt+2) in flight; only drains fully at the ramp.
      if (kt + 2 < NTk) asm volatile("s_waitcnt vmcnt(4)\n\ts_barrier" ::: "memory");
      else              asm volatile("s_waitcnt vmcnt(0)\n\ts_barrier" ::: "memory");

      // next tile's B frags: their drain overlaps the c2 MFMA cluster
      const u16* sBn = smem + 32768 + ((kt + 1) & 3) * 8192;
      bf16x8 bn[4];
#pragma unroll
      for (int j = 0; j < 4; ++j) bn[j] = *(const bf16x8*)(sBn + addrB[j]);

      __builtin_amdgcn_s_setprio(1);
#pragma unroll
      for (int i = 0; i < 4; ++i)
#pragma unroll
        for (int j = 0; j < 4; ++j)
          acc[4 + i][j] = __builtin_amdgcn_mfma_f32_16x16x32_bf16(a47[i], bcur[j], acc[4 + i][j], 0, 0, 0);
      __builtin_amdgcn_s_setprio(0);

#pragma unroll
      for (int j = 0; j < 4; ++j) bcur[j] = bn[j];
    } else {
#pragma unroll
      for (int i = 0; i < 4; ++i)
#pragma unroll
        for (int j = 0; j < 4; ++j)
          acc[4 + i][j] = __builtin_amdgcn_mfma_f32_16x16x32_bf16(a47[i], bcur[j], acc[4 + i][j], 0, 0, 0);
    }
  }

  // epilogue scratch overlaps ring slots -> full sync first
  __syncthreads();

  // -------- epilogue: per-wave LDS repack -> coalesced 16B stores --------
  float bvj[4];
#pragma unroll
  for (int j = 0; j < 4; ++j)
    bvj[j] = bias ? bias[n0 + wn * 64 + j * 16 + l15] : 0.0f;

  if (flagOut && (*flag)) {
    // fp32 output: per m-frag 16 rows x 64 cols (stride 68 f32)
    float* scrf = (float*)smem + wave * 1088;
    float* Cf = (float*)C;
#pragma unroll
    for (int i = 0; i < 8; ++i) {
#pragma unroll
      for (int j = 0; j < 4; ++j)
#pragma unroll
        for (int rr = 0; rr < 4; ++rr)
          scrf[(quad * 4 + rr) * 68 + j * 16 + l15] = acc[i][j][rr] + bvj[j];
#pragma unroll
      for (int u = lane; u < 256; u += 64) {
        const int row = u >> 4, gr = u & 15;
        float4 vv = *(const float4*)(scrf + row * 68 + gr * 4);
        *(float4*)(Cf + (m0 + wm * 128 + i * 16 + row) * (size_t)N + n0 + wn * 64 + gr * 4) = vv;
      }
    }
  } else {
    // bf16 output: per m-frag 16 rows x 64 cols (stride 72 u16)
    u16* scr = smem + wave * 1152;
    u16* Cb = (u16*)C;
#pragma unroll
    for (int i = 0; i < 8; ++i) {
#pragma unroll
      for (int j = 0; j < 4; ++j)
#pragma unroll
        for (int rr = 0; rr < 4; ++rr)
          scr[(quad * 4 + rr) * 72 + j * 16 + l15] = f2bf(acc[i][j][rr] + bvj[j]);
#pragma unroll
      for (int u = lane; u < 128; u += 64) {
        const int row = u >> 3, gr = u & 7;
        int4 vv = *(const int4*)(scr + row * 72 + gr * 8);
        *(int4*)(Cb + (m0 + wm * 128 + i * 16 + row) * (size_t)N + n0 + wn * 64 + gr * 8) = vv;
      }
    }
  }
}

// ---------------- windowed attention ----------------
// one block (4 waves) per (b, l, head). K staged in LDS (XOR-64), V^T and P at
// stride 208 (2-way banks = free). LDS total 79.2 KB -> 2 blocks/CU.
__global__ __launch_bounds__(256, 2) void attn_win(
    const u16* __restrict__ qkv, u16* __restrict__ o)
{
  __shared__ u16 Ks[196 * 64];      // slot16B = row*8 + (g ^ (row&7))
  __shared__ u16 Vt[64 * 208];      // Vt[d][n], cols >=196 zero
  __shared__ u16 Pb[4][16 * 208];   // per-wave strip
  __shared__ int gtok[208];

  const int bid = blockIdx.x;
  const int h = bid % 12;
  const int l = (bid / 12) % 16;
  const int b = bid / 192;
  const int wr0 = (l >> 2) * 14, wc0 = (l & 3) * 14;
  const int baseTok = b * 3136;

  const int t = threadIdx.x, wave = t >> 6, lane = t & 63;
  const int quad = lane >> 4, l15 = lane & 15;

  if (t < 208) {
    const int nn = t < 196 ? t : 195;
    gtok[t] = baseTok + (wr0 + nn / 14) * 56 + wc0 + nn % 14;
  }
  __syncthreads();

  // stage K (rows 0..195, 8 d-groups, XOR layout)
  for (int u = t; u < 196 * 8; u += 256) {
    const int row = u >> 3, gg = u & 7;
    int4 kv = *(const int4*)(qkv + (size_t)gtok[row] * 2304 + 768 + h * 64 + gg * 8);
    *(int4*)(Ks + (row * 8 + (gg ^ (row & 7))) * 8) = kv;
  }
  // stage V transposed: Vt[d][n]
  for (int u = t; u < 208 * 8; u += 256) {
    const int n = u >> 3, dg = u & 7;
    int4 vv = {0, 0, 0, 0};
    if (n < 196)
      vv = *(const int4*)(qkv + (size_t)gtok[n] * 2304 + 1536 + h * 64 + dg * 8);
    const u16* pv = (const u16*)&vv;
#pragma unroll
    for (int j = 0; j < 8; ++j) Vt[(dg * 8 + j) * 208 + n] = pv[j];
  }
  __syncthreads();

  u16* Pw = &Pb[wave][0];
  const bf16x8 zerov = {};

  for (int rt = wave; rt < 13; rt += 4) {
    const int n0r = rt * 16;
    int qn = n0r + l15; if (qn > 195) qn = 195;
    const u16* qrow = qkv + (size_t)gtok[qn] * 2304 + h * 64;
    const bf16x8 aq0 = *(const bf16x8*)(qrow + quad * 8);
    const bf16x8 aq1 = *(const bf16x8*)(qrow + 32 + quad * 8);

    floatx4 s[13];
#pragma unroll
    for (int ct = 0; ct < 13; ++ct) {
      int kr = ct * 16 + l15; if (kr > 195) kr = 195;
      const bf16x8 bk0 = *(const bf16x8*)(Ks + (kr * 8 + (quad ^ (kr & 7))) * 8);
      const bf16x8 bk1 = *(const bf16x8*)(Ks + (kr * 8 + ((quad + 4) ^ (kr & 7))) * 8);
      floatx4 z = {};
      z = __builtin_amdgcn_mfma_f32_16x16x32_bf16(aq0, bk0, z, 0, 0, 0);
      z = __builtin_amdgcn_mfma_f32_16x16x32_bf16(aq1, bk1, z, 0, 0, 0);
      s[ct] = z;
    }

    // softmax: col = ct*16+l15, rows = n0r + quad*4 + r
    float mx[4], sm[4];
#pragma unroll
    for (int r = 0; r < 4; ++r) mx[r] = -3e38f;
#pragma unroll
    for (int ct = 0; ct < 13; ++ct) {
      const bool maskct = (ct == 12) && (l15 >= 4);
#pragma unroll
      for (int r = 0; r < 4; ++r) {
        float v = s[ct][r] * 0.125f;
        if (maskct) v = -3e38f;
        s[ct][r] = v;
        mx[r] = fmaxf(mx[r], v);
      }
    }
#pragma unroll
    for (int r = 0; r < 4; ++r)
      for (int off = 1; off < 16; off <<= 1)
        mx[r] = fmaxf(mx[r], __shfl_xor(mx[r], off, 64));
#pragma unroll
    for (int r = 0; r < 4; ++r) sm[r] = 0.0f;
#pragma unroll
    for (int ct = 0; ct < 13; ++ct)
#pragma unroll
      for (int r = 0; r < 4; ++r) {
        const float p = __expf(s[ct][r] - mx[r]);
        s[ct][r] = p;
        sm[r] += p;
      }
#pragma unroll
    for (int r = 0; r < 4; ++r)
      for (int off = 1; off < 16; off <<= 1)
        sm[r] += __shfl_xor(sm[r], off, 64);

    // P -> LDS (A-layout round trip); cols 0..207 fully covered
#pragma unroll
    for (int ct = 0; ct < 13; ++ct)
#pragma unroll
      for (int r = 0; r < 4; ++r)
        Pw[(quad * 4 + r) * 208 + ct * 16 + l15] = f2bf(s[ct][r]);

    // O = P @ V: 6 full K=32 steps + masked tail (k 192..207 real)
    floatx4 oacc[4] = {};
#pragma unroll
    for (int ks = 0; ks < 6; ++ks) {
      const bf16x8 ap = *(const bf16x8*)(Pw + l15 * 208 + ks * 32 + quad * 8);
#pragma unroll
      for (int nt = 0; nt < 4; ++nt) {
        const bf16x8 bv = *(const bf16x8*)(Vt + (nt * 16 + l15) * 208 + ks * 32 + quad * 8);
        oacc[nt] = __builtin_amdgcn_mfma_f32_16x16x32_bf16(ap, bv, oacc[nt], 0, 0, 0);
      }
    }
    {
      const int off = 192 + (quad & 1) * 8;
      bf16x8 ap = *(const bf16x8*)(Pw + l15 * 208 + off);
      if (quad >= 2) ap = zerov;
#pragma unroll
      for (int nt = 0; nt < 4; ++nt) {
        const bf16x8 bv = *(const bf16x8*)(Vt + (nt * 16 + l15) * 208 + off);
        oacc[nt] = __builtin_amdgcn_mfma_f32_16x16x32_bf16(ap, bv, oacc[nt], 0, 0, 0);
      }
    }

    float rs[4];
#pragma unroll
    for (int r = 0; r < 4; ++r) rs[r] = 1.0f / sm[r];

    // O -> Pw repack -> coalesced 16B stores
#pragma unroll
    for (int nt = 0; nt < 4; ++nt)
#pragma unroll
      for (int r = 0; r < 4; ++r)
        Pw[(quad * 4 + r) * 208 + nt * 16 + l15] = f2bf(oacc[nt][r] * rs[r]);
#pragma unroll
    for (int u = lane; u < 128; u += 64) {
      const int row = u >> 3, gr = u & 7;
      const int n = n0r + row;
      if (n < 196) {
        int4 vv = *(const int4*)(Pw + row * 208 + gr * 8);
        *(int4*)(o + (size_t)gtok[n] * 768 + h * 64 + gr * 8) = vv;
      }
    }
  }
}

extern "C" void kernel_launch(void* const* d_in, const int* in_sizes, int n_in,
                              void* d_out, int out_size, void* d_ws, size_t ws_size,
                              hipStream_t stream)
{
  const void* x     = d_in[0];  // [8,3136,768]   fp32 or bf16
  const void* wqkv  = d_in[1];  // [768,2304]
  const void* wproj = d_in[2];  // [768,768]
  const void* bproj = d_in[3];  // [768]

  char* ws = (char*)d_ws;
  int*   flag   = (int*)ws;                         // 16 B
  float* bprojF = (float*)(ws + 16);                // 768 f32
  u16*   wqkvT  = (u16*)(ws + 4096);                // 2304*768 bf16
  u16*   wprojT = (u16*)(ws + 3543040);             // 768*768  bf16
  u16*   qkvbuf = (u16*)(ws + 4722688);             // 25088*2304 bf16
  u16*   xb     = (u16*)(ws + 120328192);           // 25088*768 bf16 (reused as attn out)
  u16*   attno  = xb;

  detect_k<<<1, 256, 0, stream>>>((const u16*)wqkv, flag);
  cast_x_k<<<dim3(18816), 256, 0, stream>>>(x, xb, 4816896, flag);
  ct_transpose_k<<<dim3(72, 24), 256, 0, stream>>>(wqkv, wqkvT, 768, 2304, flag);
  ct_transpose_k<<<dim3(24, 24), 256, 0, stream>>>(wproj, wprojT, 768, 768, flag);
  bias_cast_k<<<dim3(3), 256, 0, stream>>>(bproj, bprojF, 768, flag);

  // QKV: M=25088 (98 tiles), N=2304 (9 tiles), K=768 -> 882 blocks
  gemm256<<<dim3(882), 512, 0, stream>>>(xb, wqkvT, (const float*)nullptr, qkvbuf,
                                         25088, 2304, 768, flag, 0);
  attn_win<<<dim3(1536), 256, 0, stream>>>(qkvbuf, attno);
  // proj: M=25088 (98 tiles), N=768 (3 tiles), K=768 -> 294 blocks
  gemm256<<<dim3(294), 512, 0, stream>>>(attno, wprojT, bprojF, d_out,
                                         25088, 768, 768, flag, 1);
}

// Round 5
// 386.676 us; speedup vs baseline: 4.2347x; 1.0105x over previous
//
#include <hip/hip_runtime.h>

typedef unsigned short u16;
typedef __attribute__((ext_vector_type(8))) __bf16 bf16x8;
typedef __attribute__((ext_vector_type(4))) float floatx4;

__device__ inline float bf2f(u16 u) {
  union { unsigned u; float f; } v; v.u = ((unsigned)u) << 16; return v.f;
}
__device__ inline u16 f2bf(float f) {
  union { float f; unsigned u; } v; v.f = f;
  unsigned r = v.u + 0x7fffu + ((v.u >> 16) & 1u);
  return (u16)(r >> 16);
}

__device__ inline void glds16(const u16* g, u16* l) {
  __builtin_amdgcn_global_load_lds((const __attribute__((address_space(1))) void*)g,
                                   (__attribute__((address_space(3))) void*)l, 16, 0, 0);
}

// ---------------- dtype probe: fp32-as-u16 halves have wild exponents ----------------
__global__ __launch_bounds__(256) void detect_k(const u16* __restrict__ w, int* flag)
{
  __shared__ int cnt;
  if (threadIdx.x == 0) cnt = 0;
  __syncthreads();
  int c = 0;
  for (int i = threadIdx.x; i < 16384; i += 256) {
    const int e = (w[i] >> 7) & 0xFF;
    if (e < 64 || e > 191) ++c;
  }
  atomicAdd(&cnt, c);
  __syncthreads();
  if (threadIdx.x == 0) *flag = (cnt > 256) ? 1 : 0;   // 1 => inputs are fp32
}

// ---------------- x -> bf16 (copy or downcast), 4 elems/thread ----------------
__global__ __launch_bounds__(256) void cast_x_k(const void* __restrict__ in,
                                                u16* __restrict__ out,
                                                int n4, const int* __restrict__ flag)
{
  const int i = blockIdx.x * 256 + threadIdx.x;
  if (i >= n4) return;
  if (*flag) {
    const float4 v = ((const float4*)in)[i];
    u16 o0 = f2bf(v.x), o1 = f2bf(v.y), o2 = f2bf(v.z), o3 = f2bf(v.w);
    uint2 p; p.x = (unsigned)o0 | ((unsigned)o1 << 16); p.y = (unsigned)o2 | ((unsigned)o3 << 16);
    ((uint2*)out)[i] = p;
  } else {
    ((uint2*)out)[i] = ((const uint2*)in)[i];
  }
}

// ---------------- cast+transpose: in [R,C] (flag? f32 : bf16) -> bf16 [C,R] ----------------
__global__ __launch_bounds__(256) void ct_transpose_k(const void* __restrict__ in,
                                                      u16* __restrict__ out,
                                                      int R, int C, const int* __restrict__ flag)
{
  __shared__ u16 tile[32][33];
  const int f = *flag;
  const int c0 = blockIdx.x * 32, r0 = blockIdx.y * 32;
  const int tx = threadIdx.x & 31, ty = threadIdx.x >> 5;
#pragma unroll
  for (int i = ty; i < 32; i += 8) {
    const size_t idx = (size_t)(r0 + i) * C + (c0 + tx);
    tile[i][tx] = f ? f2bf(((const float*)in)[idx]) : ((const u16*)in)[idx];
  }
  __syncthreads();
#pragma unroll
  for (int i = ty; i < 32; i += 8)
    out[(size_t)(c0 + i) * R + (r0 + tx)] = tile[tx][i];
}

// ---------------- bias -> fp32 ----------------
__global__ __launch_bounds__(256) void bias_cast_k(const void* __restrict__ in,
                                                   float* __restrict__ out,
                                                   int n, const int* __restrict__ flag)
{
  const int i = blockIdx.x * 256 + threadIdx.x;
  if (i >= n) return;
  out[i] = *flag ? ((const float*)in)[i] : bf2f(((const u16*)in)[i]);
}

// ---------------- GEMM C[M,N] = A[M,K] @ Bt[N,K]^T (+bias), bf16 MFMA ----------------
// 224x256 tile, 8 waves (2M x 4N), BK=32, 4-slot LDS ring (120 KiB), 1 block/CU.
// Full software pipeline within the register budget (acc[7][4] = 112 AGPR frees
// room): c1 = a0-2 x b (12 MFMA) covers the a3-6 ds_reads issued at tile top;
// c2 = a3-6 x b (16 MFMA) covers the NEXT tile's b + a0-2 ds_reads issued after
// the single mid-tile fused counted-vmcnt + barrier. Every read burst is overlapped
// by an MFMA cluster that depends only on already-resident registers. One barrier
// per K-tile (ring-4 overwrite safety: all slot-(kt-2) reads lgkm-retire in
// c2(kt-2), which precedes every wave's mid(kt-1) rendezvous, which precedes the
// DMA(kt+2) issue). M-tile 224 also fixes grid quantization: QKV 1008 blocks =
// 3.94 rounds (waste 1.6% vs 13.9% at 882). A-staging is 896 16B-slots -> waves
// 0-5 issue 2 A-ops, waves 6-7 one => wave-uniform vmcnt(4)/vmcnt(3) branch.
// Loop unrolled x2 with named ping/pong frag sets (no runtime-indexed regs).
// Requires M%224==0, N%256==0, K%32==0, K>=96, NTk even.
__global__ __launch_bounds__(512, 2) void gemm256(
    const u16* __restrict__ A, const u16* __restrict__ Bt,
    const float* __restrict__ bias, void* __restrict__ C,
    int M, int N, int K, const int* __restrict__ flag, int flagOut)
{
  __shared__ u16 smem[61440];   // A ring: 4 x 7168 u16, B ring: 4 x 8192 u16
  u16* As = smem;
  u16* Bs = smem + 28672;
  const int t = threadIdx.x;
  const int wave = t >> 6, lane = t & 63;
  const int quad = lane >> 4, l15 = lane & 15;
  const int wm = wave >> 2, wn = wave & 3;

  // bijective XCD swizzle, then M-major so consecutive blocks in an XCD chunk
  // share the B-panel (L2-resident)
  const int nwg = gridDim.x;
  const int q = nwg >> 3, r8 = nwg & 7;
  const int xcd = blockIdx.x & 7, loc = blockIdx.x >> 3;
  const int wg = (xcd < r8 ? xcd * (q + 1) : r8 * (q + 1) + (xcd - r8) * q) + loc;
  const int MT = M / 224;
  const int mt = wg % MT, ntile = wg / MT;
  const size_t m0 = (size_t)mt * 224;
  const size_t n0 = (size_t)ntile << 8;

  // LDS read offsets (u16 units within one tile slot).
  // Layout: line = row>>1 (128 B), slot h = (row&1)*4 + kgroup, stored h^(line&7).
  int addrA[7], addrB[4];
#pragma unroll
  for (int i = 0; i < 7; ++i) {
    const int row = wm * 112 + i * 16 + l15;
    const int hs = (((row & 1) << 2) | quad) ^ ((row >> 1) & 7);
    addrA[i] = (row >> 1) * 64 + hs * 8;
  }
#pragma unroll
  for (int j = 0; j < 4; ++j) {
    const int row = wn * 64 + j * 16 + l15;
    const int hs = (((row & 1) << 2) | quad) ^ ((row >> 1) & 7);
    addrB[j] = (row >> 1) * 64 + hs * 8;
  }

  // staging: invert the swizzle to find (row, kgroup) fetched into stored slot S.
  // A tile = 896 slots: p0 covers S=t (all), p1 covers S=512+t (t<384 => waves 0-5).
  // B tile = 1024 slots: p0 S=t, p1 S=512+t (all threads).
  const u16 *aSrc0, *aSrc1, *bSrc0, *bSrc1;
  {
    const int S0 = t, S1 = 512 + t;
    int line = S0 >> 3, h = (S0 & 7) ^ (line & 7);
    int row = line * 2 + (h >> 2), g = (h & 3) * 8;
    aSrc0 = A + (m0 + row) * (size_t)K + g;
    bSrc0 = Bt + (n0 + row) * (size_t)K + g;
    line = S1 >> 3; h = (S1 & 7) ^ (line & 7);
    row = line * 2 + (h >> 2); g = (h & 3) * 8;
    aSrc1 = A + (m0 + row) * (size_t)K + g;     // valid only for t<384 (row<224)
    bSrc1 = Bt + (n0 + row) * (size_t)K + g;
  }
  const int dst0 = wave * 512;          // u16 units; HW adds lane*16B
  const int dst1 = 4096 + wave * 512;

  const int NTk = K >> 5;
  floatx4 acc[7][4] = {};

  // prologue: stage K-tiles 0,1
#pragma unroll
  for (int pt = 0; pt < 2; ++pt) {
    glds16(aSrc0 + pt * 32, As + pt * 7168 + dst0);
    if (wave < 6) glds16(aSrc1 + pt * 32, As + pt * 7168 + dst1);
    glds16(bSrc0 + pt * 32, Bs + pt * 8192 + dst0);
    glds16(bSrc1 + pt * 32, Bs + pt * 8192 + dst1);
  }
  if (wave < 6) asm volatile("s_waitcnt vmcnt(4)" ::: "memory");
  else          asm volatile("s_waitcnt vmcnt(3)" ::: "memory");
  asm volatile("s_barrier" ::: "memory");

  // tile-0 current frag set
  bf16x8 bP[4], a02P[3], bQ[4], a02Q[3];
#pragma unroll
  for (int j = 0; j < 4; ++j) bP[j] = *(const bf16x8*)(Bs + addrB[j]);
#pragma unroll
  for (int i = 0; i < 3; ++i) a02P[i] = *(const bf16x8*)(As + addrA[i]);

#define TILE_BODY(kt, bC, a02C, bN, a02N)                                          \
  {                                                                                \
    const u16* sA_ = As + ((kt) & 3) * 7168;                                       \
    if ((kt) + 2 < NTk) {                                                          \
      const int pre_ = ((kt) + 2) * 32;                                            \
      const int pr_ = ((kt) + 2) & 3;                                              \
      glds16(aSrc0 + pre_, As + pr_ * 7168 + dst0);                                \
      if (wave < 6) glds16(aSrc1 + pre_, As + pr_ * 7168 + dst1);                  \
      glds16(bSrc0 + pre_, Bs + pr_ * 8192 + dst0);                                \
      glds16(bSrc1 + pre_, Bs + pr_ * 8192 + dst1);                                \
    }                                                                              \
    bf16x8 a36_0 = *(const bf16x8*)(sA_ + addrA[3]);                               \
    bf16x8 a36_1 = *(const bf16x8*)(sA_ + addrA[4]);                               \
    bf16x8 a36_2 = *(const bf16x8*)(sA_ + addrA[5]);                               \
    bf16x8 a36_3 = *(const bf16x8*)(sA_ + addrA[6]);                               \
    __builtin_amdgcn_s_setprio(1);                                                 \
    _Pragma("unroll")                                                              \
    for (int i = 0; i < 3; ++i)                                                    \
      _Pragma("unroll")                                                            \
      for (int j = 0; j < 4; ++j)                                                  \
        acc[i][j] = __builtin_amdgcn_mfma_f32_16x16x32_bf16(a02C[i], bC[j], acc[i][j], 0, 0, 0); \
    __builtin_amdgcn_s_setprio(0);                                                 \
    if ((kt) + 2 < NTk) {                                                          \
      if (wave < 6) asm volatile("s_waitcnt vmcnt(4)" ::: "memory");               \
      else          asm volatile("s_waitcnt vmcnt(3)" ::: "memory");               \
      asm volatile("s_barrier" ::: "memory");                                      \
    } else if ((kt) + 1 < NTk) {                                                   \
      asm volatile("s_waitcnt vmcnt(0)" ::: "memory");                             \
      asm volatile("s_barrier" ::: "memory");                                      \
    }                                                                              \
    if ((kt) + 1 < NTk) {                                                          \
      const u16* sAn_ = As + (((kt) + 1) & 3) * 7168;                              \
      const u16* sBn_ = Bs + (((kt) + 1) & 3) * 8192;                              \
      _Pragma("unroll")                                                            \
      for (int j = 0; j < 4; ++j) bN[j] = *(const bf16x8*)(sBn_ + addrB[j]);       \
      _Pragma("unroll")                                                            \
      for (int i = 0; i < 3; ++i) a02N[i] = *(const bf16x8*)(sAn_ + addrA[i]);     \
    }                                                                              \
    __builtin_amdgcn_s_setprio(1);                                                 \
    _Pragma("unroll")                                                              \
    for (int j = 0; j < 4; ++j) {                                                  \
      acc[3][j] = __builtin_amdgcn_mfma_f32_16x16x32_bf16(a36_0, bC[j], acc[3][j], 0, 0, 0); \
      acc[4][j] = __builtin_amdgcn_mfma_f32_16x16x32_bf16(a36_1, bC[j], acc[4][j], 0, 0, 0); \
      acc[5][j] = __builtin_amdgcn_mfma_f32_16x16x32_bf16(a36_2, bC[j], acc[5][j], 0, 0, 0); \
      acc[6][j] = __builtin_amdgcn_mfma_f32_16x16x32_bf16(a36_3, bC[j], acc[6][j], 0, 0, 0); \
    }                                                                              \
    __builtin_amdgcn_s_setprio(0);                                                 \
  }

  for (int kt = 0; kt < NTk; kt += 2) {
    TILE_BODY(kt, bP, a02P, bQ, a02Q);
    TILE_BODY(kt + 1, bQ, a02Q, bP, a02P);
  }
#undef TILE_BODY

  // epilogue scratch overlaps ring slots -> full sync first
  __syncthreads();

  // -------- epilogue: per-wave LDS repack -> coalesced 16B stores --------
  float bvj[4];
#pragma unroll
  for (int j = 0; j < 4; ++j)
    bvj[j] = bias ? bias[n0 + wn * 64 + j * 16 + l15] : 0.0f;

  if (flagOut && (*flag)) {
    // fp32 output: per m-frag 16 rows x 64 cols (stride 68 f32)
    float* scrf = (float*)smem + wave * 1088;
    float* Cf = (float*)C;
#pragma unroll
    for (int i = 0; i < 7; ++i) {
#pragma unroll
      for (int j = 0; j < 4; ++j)
#pragma unroll
        for (int rr = 0; rr < 4; ++rr)
          scrf[(quad * 4 + rr) * 68 + j * 16 + l15] = acc[i][j][rr] + bvj[j];
#pragma unroll
      for (int u = lane; u < 256; u += 64) {
        const int row = u >> 4, gr = u & 15;
        float4 vv = *(const float4*)(scrf + row * 68 + gr * 4);
        *(float4*)(Cf + (m0 + wm * 112 + i * 16 + row) * (size_t)N + n0 + wn * 64 + gr * 4) = vv;
      }
    }
  } else {
    // bf16 output: per m-frag 16 rows x 64 cols (stride 72 u16)
    u16* scr = smem + wave * 1152;
    u16* Cb = (u16*)C;
#pragma unroll
    for (int i = 0; i < 7; ++i) {
#pragma unroll
      for (int j = 0; j < 4; ++j)
#pragma unroll
        for (int rr = 0; rr < 4; ++rr)
          scr[(quad * 4 + rr) * 72 + j * 16 + l15] = f2bf(acc[i][j][rr] + bvj[j]);
#pragma unroll
      for (int u = lane; u < 128; u += 64) {
        const int row = u >> 3, gr = u & 7;
        int4 vv = *(const int4*)(scr + row * 72 + gr * 8);
        *(int4*)(Cb + (m0 + wm * 112 + i * 16 + row) * (size_t)N + n0 + wn * 64 + gr * 8) = vv;
      }
    }
  }
}

// ---------------- windowed attention ----------------
// one block (4 waves) per (b, l, head). K staged in LDS (XOR-64), V^T and P at
// stride 208 (2-way banks = free). LDS total 79.2 KB -> 2 blocks/CU.
__global__ __launch_bounds__(256, 2) void attn_win(
    const u16* __restrict__ qkv, u16* __restrict__ o)
{
  __shared__ u16 Ks[196 * 64];      // slot16B = row*8 + (g ^ (row&7))
  __shared__ u16 Vt[64 * 208];      // Vt[d][n], cols >=196 zero
  __shared__ u16 Pb[4][16 * 208];   // per-wave strip
  __shared__ int gtok[208];

  const int bid = blockIdx.x;
  const int h = bid % 12;
  const int l = (bid / 12) % 16;
  const int b = bid / 192;
  const int wr0 = (l >> 2) * 14, wc0 = (l & 3) * 14;
  const int baseTok = b * 3136;

  const int t = threadIdx.x, wave = t >> 6, lane = t & 63;
  const int quad = lane >> 4, l15 = lane & 15;

  if (t < 208) {
    const int nn = t < 196 ? t : 195;
    gtok[t] = baseTok + (wr0 + nn / 14) * 56 + wc0 + nn % 14;
  }
  __syncthreads();

  // stage K (rows 0..195, 8 d-groups, XOR layout)
  for (int u = t; u < 196 * 8; u += 256) {
    const int row = u >> 3, gg = u & 7;
    int4 kv = *(const int4*)(qkv + (size_t)gtok[row] * 2304 + 768 + h * 64 + gg * 8);
    *(int4*)(Ks + (row * 8 + (gg ^ (row & 7))) * 8) = kv;
  }
  // stage V transposed: Vt[d][n]
  for (int u = t; u < 208 * 8; u += 256) {
    const int n = u >> 3, dg = u & 7;
    int4 vv = {0, 0, 0, 0};
    if (n < 196)
      vv = *(const int4*)(qkv + (size_t)gtok[n] * 2304 + 1536 + h * 64 + dg * 8);
    const u16* pv = (const u16*)&vv;
#pragma unroll
    for (int j = 0; j < 8; ++j) Vt[(dg * 8 + j) * 208 + n] = pv[j];
  }
  __syncthreads();

  u16* Pw = &Pb[wave][0];
  const bf16x8 zerov = {};

  for (int rt = wave; rt < 13; rt += 4) {
    const int n0r = rt * 16;
    int qn = n0r + l15; if (qn > 195) qn = 195;
    const u16* qrow = qkv + (size_t)gtok[qn] * 2304 + h * 64;
    const bf16x8 aq0 = *(const bf16x8*)(qrow + quad * 8);
    const bf16x8 aq1 = *(const bf16x8*)(qrow + 32 + quad * 8);

    floatx4 s[13];
#pragma unroll
    for (int ct = 0; ct < 13; ++ct) {
      int kr = ct * 16 + l15; if (kr > 195) kr = 195;
      const bf16x8 bk0 = *(const bf16x8*)(Ks + (kr * 8 + (quad ^ (kr & 7))) * 8);
      const bf16x8 bk1 = *(const bf16x8*)(Ks + (kr * 8 + ((quad + 4) ^ (kr & 7))) * 8);
      floatx4 z = {};
      z = __builtin_amdgcn_mfma_f32_16x16x32_bf16(aq0, bk0, z, 0, 0, 0);
      z = __builtin_amdgcn_mfma_f32_16x16x32_bf16(aq1, bk1, z, 0, 0, 0);
      s[ct] = z;
    }

    // softmax: col = ct*16+l15, rows = n0r + quad*4 + r
    float mx[4], sm[4];
#pragma unroll
    for (int r = 0; r < 4; ++r) mx[r] = -3e38f;
#pragma unroll
    for (int ct = 0; ct < 13; ++ct) {
      const bool maskct = (ct == 12) && (l15 >= 4);
#pragma unroll
      for (int r = 0; r < 4; ++r) {
        float v = s[ct][r] * 0.125f;
        if (maskct) v = -3e38f;
        s[ct][r] = v;
        mx[r] = fmaxf(mx[r], v);
      }
    }
#pragma unroll
    for (int r = 0; r < 4; ++r)
      for (int off = 1; off < 16; off <<= 1)
        mx[r] = fmaxf(mx[r], __shfl_xor(mx[r], off, 64));
#pragma unroll
    for (int r = 0; r < 4; ++r) sm[r] = 0.0f;
#pragma unroll
    for (int ct = 0; ct < 13; ++ct)
#pragma unroll
      for (int r = 0; r < 4; ++r) {
        const float p = __expf(s[ct][r] - mx[r]);
        s[ct][r] = p;
        sm[r] += p;
      }
#pragma unroll
    for (int r = 0; r < 4; ++r)
      for (int off = 1; off < 16; off <<= 1)
        sm[r] += __shfl_xor(sm[r], off, 64);

    // P -> LDS (A-layout round trip); cols 0..207 fully covered
#pragma unroll
    for (int ct = 0; ct < 13; ++ct)
#pragma unroll
      for (int r = 0; r < 4; ++r)
        Pw[(quad * 4 + r) * 208 + ct * 16 + l15] = f2bf(s[ct][r]);

    // O = P @ V: 6 full K=32 steps + masked tail (k 192..207 real)
    floatx4 oacc[4] = {};
#pragma unroll
    for (int ks = 0; ks < 6; ++ks) {
      const bf16x8 ap = *(const bf16x8*)(Pw + l15 * 208 + ks * 32 + quad * 8);
#pragma unroll
      for (int nt = 0; nt < 4; ++nt) {
        const bf16x8 bv = *(const bf16x8*)(Vt + (nt * 16 + l15) * 208 + ks * 32 + quad * 8);
        oacc[nt] = __builtin_amdgcn_mfma_f32_16x16x32_bf16(ap, bv, oacc[nt], 0, 0, 0);
      }
    }
    {
      const int off = 192 + (quad & 1) * 8;
      bf16x8 ap = *(const bf16x8*)(Pw + l15 * 208 + off);
      if (quad >= 2) ap = zerov;
#pragma unroll
      for (int nt = 0; nt < 4; ++nt) {
        const bf16x8 bv = *(const bf16x8*)(Vt + (nt * 16 + l15) * 208 + off);
        oacc[nt] = __builtin_amdgcn_mfma_f32_16x16x32_bf16(ap, bv, oacc[nt], 0, 0, 0);
      }
    }

    float rs[4];
#pragma unroll
    for (int r = 0; r < 4; ++r) rs[r] = 1.0f / sm[r];

    // O -> Pw repack -> coalesced 16B stores
#pragma unroll
    for (int nt = 0; nt < 4; ++nt)
#pragma unroll
      for (int r = 0; r < 4; ++r)
        Pw[(quad * 4 + r) * 208 + nt * 16 + l15] = f2bf(oacc[nt][r] * rs[r]);
#pragma unroll
    for (int u = lane; u < 128; u += 64) {
      const int row = u >> 3, gr = u & 7;
      const int n = n0r + row;
      if (n < 196) {
        int4 vv = *(const int4*)(Pw + row * 208 + gr * 8);
        *(int4*)(o + (size_t)gtok[n] * 768 + h * 64 + gr * 8) = vv;
      }
    }
  }
}

extern "C" void kernel_launch(void* const* d_in, const int* in_sizes, int n_in,
                              void* d_out, int out_size, void* d_ws, size_t ws_size,
                              hipStream_t stream)
{
  const void* x     = d_in[0];  // [8,3136,768]   fp32 or bf16
  const void* wqkv  = d_in[1];  // [768,2304]
  const void* wproj = d_in[2];  // [768,768]
  const void* bproj = d_in[3];  // [768]

  char* ws = (char*)d_ws;
  int*   flag   = (int*)ws;                         // 16 B
  float* bprojF = (float*)(ws + 16);                // 768 f32
  u16*   wqkvT  = (u16*)(ws + 4096);                // 2304*768 bf16
  u16*   wprojT = (u16*)(ws + 3543040);             // 768*768  bf16
  u16*   qkvbuf = (u16*)(ws + 4722688);             // 25088*2304 bf16
  u16*   xb     = (u16*)(ws + 120328192);           // 25088*768 bf16 (reused as attn out)
  u16*   attno  = xb;

  detect_k<<<1, 256, 0, stream>>>((const u16*)wqkv, flag);
  cast_x_k<<<dim3(18816), 256, 0, stream>>>(x, xb, 4816896, flag);
  ct_transpose_k<<<dim3(72, 24), 256, 0, stream>>>(wqkv, wqkvT, 768, 2304, flag);
  ct_transpose_k<<<dim3(24, 24), 256, 0, stream>>>(wproj, wprojT, 768, 768, flag);
  bias_cast_k<<<dim3(3), 256, 0, stream>>>(bproj, bprojF, 768, flag);

  // QKV: M=25088 (112 tiles of 224), N=2304 (9 tiles) -> 1008 blocks (3.94 rounds)
  gemm256<<<dim3(1008), 512, 0, stream>>>(xb, wqkvT, (const float*)nullptr, qkvbuf,
                                          25088, 2304, 768, flag, 0);
  attn_win<<<dim3(1536), 256, 0, stream>>>(qkvbuf, attno);
  // proj: M=25088 (112 tiles), N=768 (3 tiles) -> 336 blocks
  gemm256<<<dim3(336), 512, 0, stream>>>(attno, wprojT, bprojF, d_out,
                                         25088, 768, 768, flag, 1);
}